// Round 2
// baseline (719.233 us; speedup 1.0000x reference)
//
#include <hip/hip_runtime.h>
#include <hip/hip_bf16.h>

typedef unsigned short ushort_t;
typedef __bf16 bf16x8 __attribute__((ext_vector_type(8)));
typedef float f32x4 __attribute__((ext_vector_type(4)));

#define B_  32
#define C_  2048
#define Q_  512
#define H_  1024
#define K2_ 1024  // hi|lo packed K dimension per operand

// float -> bf16 round-to-nearest-even
__device__ __forceinline__ unsigned short f2bf(float f) {
  unsigned u = __float_as_uint(f);
  u += 0x7FFFu + ((u >> 16) & 1u);
  return (unsigned short)(u >> 16);
}
__device__ __forceinline__ float bf2f(unsigned short h) {
  return __uint_as_float(((unsigned)h) << 16);
}

// ---------------------------------------------------------------------------
// K1: per-row softmax over Q=512, emit bf16 hi|lo split.
// One wave per (b,c) row: 64 lanes x 8 contiguous floats.
// attn layout: [B*C][1024] ushort, cols [0,512) = hi, [512,1024) = lo.
// ---------------------------------------------------------------------------
__global__ __launch_bounds__(256) void softmax_split(const float* __restrict__ sim,
                                                     ushort_t* __restrict__ attn) {
  const int row  = (blockIdx.x << 2) | (threadIdx.x >> 6);
  const int lane = threadIdx.x & 63;
  const float4* rp = reinterpret_cast<const float4*>(sim + (size_t)row * Q_);
  float4 v0 = rp[lane * 2];
  float4 v1 = rp[lane * 2 + 1];
  float x[8] = {v0.x, v0.y, v0.z, v0.w, v1.x, v1.y, v1.z, v1.w};

  float mx = x[0];
#pragma unroll
  for (int j = 1; j < 8; ++j) mx = fmaxf(mx, x[j]);
#pragma unroll
  for (int s = 32; s > 0; s >>= 1) mx = fmaxf(mx, __shfl_xor(mx, s, 64));

  float e[8], sum = 0.f;
#pragma unroll
  for (int j = 0; j < 8; ++j) { e[j] = __expf(x[j] - mx); sum += e[j]; }
#pragma unroll
  for (int s = 32; s > 0; s >>= 1) sum += __shfl_xor(sum, s, 64);
  const float inv = 1.0f / sum;

  union { ushort_t s[8]; uint4 v; } hi, lo;
#pragma unroll
  for (int j = 0; j < 8; ++j) {
    float w = e[j] * inv;
    unsigned short h = f2bf(w);
    hi.s[j] = h;
    lo.s[j] = f2bf(w - bf2f(h));
  }
  ushort_t* orow = attn + (size_t)row * K2_;
  *reinterpret_cast<uint4*>(orow + lane * 8)      = hi.v;
  *reinterpret_cast<uint4*>(orow + Q_ + lane * 8) = lo.v;
}

// ---------------------------------------------------------------------------
// K1b: transpose-convert qencode [B][Q][H] f32 -> qt [B][H][1024] bf16,
// qt[b][h][q] = hi(qenc[b][q][h]), qt[b][h][512+q] = lo(...).
// 64x64 LDS tile transpose per block.
// ---------------------------------------------------------------------------
__global__ __launch_bounds__(256) void qenc_convert(const float* __restrict__ qe,
                                                    ushort_t* __restrict__ qt) {
  __shared__ float tile[64][65];
  const int b  = blockIdx.z;
  const int q0 = blockIdx.y << 6;
  const int h0 = blockIdx.x << 6;
  const int tx = threadIdx.x & 63;
  const int ty = threadIdx.x >> 6;

  const float* src = qe + ((size_t)b * Q_ + q0) * H_ + h0;
#pragma unroll
  for (int s = 0; s < 64; s += 4)
    tile[s + ty][tx] = src[(size_t)(s + ty) * H_ + tx];
  __syncthreads();

  const int hh = threadIdx.x >> 2;         // 0..63  (output row within h-tile)
  const int qs = (threadIdx.x & 3) << 4;   // 0,16,32,48 (q start within tile)
  ushort_t* dst = qt + ((size_t)b * H_ + h0 + hh) * K2_ + q0 + qs;

  union { ushort_t s[8]; uint4 v; } ha, hb, la, lb;
#pragma unroll
  for (int j = 0; j < 8; ++j) {
    float f = tile[qs + j][hh];
    unsigned short fh = f2bf(f);
    ha.s[j] = fh; la.s[j] = f2bf(f - bf2f(fh));
    float g = tile[qs + 8 + j][hh];
    unsigned short gh = f2bf(g);
    hb.s[j] = gh; lb.s[j] = f2bf(g - bf2f(gh));
  }
  *reinterpret_cast<uint4*>(dst)          = ha.v;
  *reinterpret_cast<uint4*>(dst + 8)      = hb.v;
  *reinterpret_cast<uint4*>(dst + Q_)     = la.v;
  *reinterpret_cast<uint4*>(dst + Q_ + 8) = lb.v;
}

// ---------------------------------------------------------------------------
// K2: per-batch GEMM  out[c][h] = sum_k A'[c][k] * Bt[h][k]
// 3-term split: virtual K = 1536 in segments (Ah*Qh), (Ah*Ql), (Al*Qh).
// 128x128 tile, BK=64, 4 waves (2x2 of 64x64), mfma_f32_16x16x32_bf16.
// ---------------------------------------------------------------------------
__global__ __launch_bounds__(256) void gemm_bt(const ushort_t* __restrict__ A,
                                               const ushort_t* __restrict__ Bt,
                                               float* __restrict__ out) {
  constexpr int BK = 64;
  __shared__ ushort_t As[128 * BK];
  __shared__ ushort_t Bs[128 * BK];

  const int b  = blockIdx.z;
  const int h0 = blockIdx.x << 7;
  const int c0 = blockIdx.y << 7;
  const int t    = threadIdx.x;
  const int lane = t & 63;
  const int w    = t >> 6;
  const int wm = (w >> 1) << 6;  // wave row offset: 0 / 64
  const int wn = (w & 1) << 6;   // wave col offset: 0 / 64

  const ushort_t* Ab = A  + (size_t)b * C_ * K2_;
  const ushort_t* Bb = Bt + (size_t)b * H_ * K2_;

  f32x4 acc[4][4];
#pragma unroll
  for (int m = 0; m < 4; ++m)
#pragma unroll
    for (int n = 0; n < 4; ++n) acc[m][n] = (f32x4){0.f, 0.f, 0.f, 0.f};

  const int fr = lane & 15;        // fragment row (A) / col (B)
  const int fk = (lane >> 4) * 8;  // fragment k-offset

  for (int kt = 0; kt < 24; ++kt) {          // 3 segments x 8 steps of BK=64
    const int seg  = kt >> 3;
    const int kOff = (kt & 7) * BK;
    const int aOff = (seg == 2) ? Q_ : 0;    // Al in segment 2
    const int bOff = (seg == 1) ? Q_ : 0;    // Ql in segment 1

    __syncthreads();  // all waves done reading previous LDS tiles
#pragma unroll
    for (int i = 0; i < 4; ++i) {
      const int id = i * 256 + t;
      const int r = id >> 3, cch = (id & 7) << 3;
      __builtin_amdgcn_global_load_lds(
          (const __attribute__((address_space(1))) unsigned*)(Ab + (size_t)(c0 + r) * K2_ + aOff + kOff + cch),
          (__attribute__((address_space(3))) unsigned*)(As + id * 8), 16, 0, 0);
    }
#pragma unroll
    for (int i = 0; i < 4; ++i) {
      const int id = i * 256 + t;
      const int r = id >> 3, cch = (id & 7) << 3;
      __builtin_amdgcn_global_load_lds(
          (const __attribute__((address_space(1))) unsigned*)(Bb + (size_t)(h0 + r) * K2_ + bOff + kOff + cch),
          (__attribute__((address_space(3))) unsigned*)(Bs + id * 8), 16, 0, 0);
    }
    asm volatile("s_waitcnt vmcnt(0)" ::: "memory");
    __syncthreads();  // staged tiles visible to all waves

#pragma unroll
    for (int ks = 0; ks < 2; ++ks) {
      const int ko = ks * 32 + fk;
      bf16x8 af[4], bfr[4];
#pragma unroll
      for (int m = 0; m < 4; ++m)
        af[m] = *reinterpret_cast<const bf16x8*>(&As[(wm + m * 16 + fr) * BK + ko]);
#pragma unroll
      for (int n = 0; n < 4; ++n)
        bfr[n] = *reinterpret_cast<const bf16x8*>(&Bs[(wn + n * 16 + fr) * BK + ko]);
#pragma unroll
      for (int m = 0; m < 4; ++m)
#pragma unroll
        for (int n = 0; n < 4; ++n)
          acc[m][n] = __builtin_amdgcn_mfma_f32_16x16x32_bf16(af[m], bfr[n], acc[m][n], 0, 0, 0);
    }
  }

  // Epilogue: C/D layout col = lane&15, row = (lane>>4)*4 + j  (m89-verified)
  float* ob = out + (size_t)b * C_ * H_;
  const int orow = c0 + wm + ((lane >> 4) << 2);
  const int ocol = h0 + wn + fr;
#pragma unroll
  for (int m = 0; m < 4; ++m)
#pragma unroll
    for (int n = 0; n < 4; ++n) {
#pragma unroll
      for (int j = 0; j < 4; ++j)
        ob[(size_t)(orow + m * 16 + j) * H_ + (ocol + n * 16)] = acc[m][n][j];
    }
}

// ---------------------------------------------------------------------------
extern "C" void kernel_launch(void* const* d_in, const int* in_sizes, int n_in,
                              void* d_out, int out_size, void* d_ws, size_t ws_size,
                              hipStream_t stream) {
  const float* sim  = (const float*)d_in[0];   // [B, C, Q] f32
  const float* qenc = (const float*)d_in[1];   // [B, Q, H] f32
  float* out = (float*)d_out;                  // [B, C, H] f32

  // workspace: attn hi|lo (128 MB) then transposed qenc hi|lo (64 MB)
  ushort_t* attn = (ushort_t*)d_ws;
  ushort_t* qt   = (ushort_t*)((char*)d_ws + (size_t)B_ * C_ * K2_ * sizeof(ushort_t));

  softmax_split<<<(B_ * C_) / 4, 256, 0, stream>>>(sim, attn);
  qenc_convert<<<dim3(H_ / 64, Q_ / 64, B_), 256, 0, stream>>>(qenc, qt);
  gemm_bt<<<dim3(H_ / 128, C_ / 128, B_), 256, 0, stream>>>(attn, qt, out);
}

// Round 5
// 518.413 us; speedup vs baseline: 1.3874x; 1.3874x over previous
//
#include <hip/hip_runtime.h>
#include <hip/hip_bf16.h>

typedef unsigned short ushort_t;
typedef __bf16 bf16x8 __attribute__((ext_vector_type(8)));
typedef float f32x4 __attribute__((ext_vector_type(4)));

#define B_  32
#define C_  2048
#define Q_  512
#define H_  1024

// float -> bf16 round-to-nearest-even
__device__ __forceinline__ unsigned short f2bf(float f) {
  unsigned u = __float_as_uint(f);
  u += 0x7FFFu + ((u >> 16) & 1u);
  return (unsigned short)(u >> 16);
}

// ---------------------------------------------------------------------------
// K1: per-row softmax over Q=512, emit bf16.
// One wave per (b,c) row: 64 lanes x 8 contiguous floats.
// attn layout: [B*C][512] ushort (bf16 weights).
// ---------------------------------------------------------------------------
__global__ __launch_bounds__(256) void softmax_bf16(const float* __restrict__ sim,
                                                    ushort_t* __restrict__ attn) {
  const int row  = (blockIdx.x << 2) | (threadIdx.x >> 6);
  const int lane = threadIdx.x & 63;
  const float4* rp = reinterpret_cast<const float4*>(sim + (size_t)row * Q_);
  float4 v0 = rp[lane * 2];
  float4 v1 = rp[lane * 2 + 1];
  float x[8] = {v0.x, v0.y, v0.z, v0.w, v1.x, v1.y, v1.z, v1.w};

  float mx = x[0];
#pragma unroll
  for (int j = 1; j < 8; ++j) mx = fmaxf(mx, x[j]);
#pragma unroll
  for (int s = 32; s > 0; s >>= 1) mx = fmaxf(mx, __shfl_xor(mx, s, 64));

  float e[8], sum = 0.f;
#pragma unroll
  for (int j = 0; j < 8; ++j) { e[j] = __expf(x[j] - mx); sum += e[j]; }
#pragma unroll
  for (int s = 32; s > 0; s >>= 1) sum += __shfl_xor(sum, s, 64);
  const float inv = 1.0f / sum;

  union { ushort_t s[8]; uint4 v; } hi;
#pragma unroll
  for (int j = 0; j < 8; ++j) hi.s[j] = f2bf(e[j] * inv);
  *reinterpret_cast<uint4*>(attn + (size_t)row * Q_ + lane * 8) = hi.v;
}

// ---------------------------------------------------------------------------
// K1b: transpose-convert qencode [B][Q][H] f32 -> qt [B][H][512] bf16,
// qt[b][h][q] = bf16(qenc[b][q][h]). 64x64 LDS tile transpose per block.
// ---------------------------------------------------------------------------
__global__ __launch_bounds__(256) void qenc_convert(const float* __restrict__ qe,
                                                    ushort_t* __restrict__ qt) {
  __shared__ float tile[64][65];
  const int b  = blockIdx.z;
  const int q0 = blockIdx.y << 6;
  const int h0 = blockIdx.x << 6;
  const int tx = threadIdx.x & 63;
  const int ty = threadIdx.x >> 6;

  const float* src = qe + ((size_t)b * Q_ + q0) * H_ + h0;
#pragma unroll
  for (int s = 0; s < 64; s += 4)
    tile[s + ty][tx] = src[(size_t)(s + ty) * H_ + tx];
  __syncthreads();

  const int hh = threadIdx.x >> 2;         // 0..63  (output row within h-tile)
  const int qs = (threadIdx.x & 3) << 4;   // 0,16,32,48 (q start within tile)
  ushort_t* dst = qt + ((size_t)b * H_ + h0 + hh) * Q_ + q0 + qs;

  union { ushort_t s[8]; uint4 v; } ha, hb;
#pragma unroll
  for (int j = 0; j < 8; ++j) {
    ha.s[j] = f2bf(tile[qs + j][hh]);
    hb.s[j] = f2bf(tile[qs + 8 + j][hh]);
  }
  *reinterpret_cast<uint4*>(dst)     = ha.v;
  *reinterpret_cast<uint4*>(dst + 8) = hb.v;
}

// ---------------------------------------------------------------------------
// K2: per-batch GEMM  out[c][h] = sum_q attn[c][q] * qt[h][q],  K = 512.
// 128x128 tile, BK=64, 4 waves (2x2 of 64x64), mfma_f32_16x16x32_bf16.
// T1 XCD swizzle: 4096 blocks, each XCD gets 512 contiguous tiles
// (= 4 whole batches; per-batch operands 3 MB < 4 MB L2).
// ---------------------------------------------------------------------------
__global__ __launch_bounds__(256) void gemm_bt(const ushort_t* __restrict__ A,
                                               const ushort_t* __restrict__ Bt,
                                               float* __restrict__ out) {
  constexpr int BK = 64;
  __shared__ ushort_t As[128 * BK];
  __shared__ ushort_t Bs[128 * BK];

  // XCD-aware swizzle (nwg = 4096, nwg % 8 == 0 -> simple bijective form)
  const int id = blockIdx.x;
  const int sw = (id & 7) * 512 + (id >> 3);
  const int b   = sw >> 7;          // batch
  const int rem = sw & 127;         // 16 c-tiles x 8 h-tiles
  const int c0 = (rem >> 3) << 7;
  const int h0 = (rem & 7) << 7;

  const int t    = threadIdx.x;
  const int lane = t & 63;
  const int w    = t >> 6;
  const int wm = (w >> 1) << 6;  // wave row offset: 0 / 64
  const int wn = (w & 1) << 6;   // wave col offset: 0 / 64

  const ushort_t* Ab = A  + (size_t)b * C_ * Q_;
  const ushort_t* Bb = Bt + (size_t)b * H_ * Q_;

  f32x4 acc[4][4];
#pragma unroll
  for (int m = 0; m < 4; ++m)
#pragma unroll
    for (int n = 0; n < 4; ++n) acc[m][n] = (f32x4){0.f, 0.f, 0.f, 0.f};

  const int fr = lane & 15;        // fragment row (A) / col (B)
  const int fk = (lane >> 4) * 8;  // fragment k-offset

  for (int kt = 0; kt < 8; ++kt) {     // K = 512, BK = 64
    const int kOff = kt * BK;

    __syncthreads();  // all waves done reading previous LDS tiles
#pragma unroll
    for (int i = 0; i < 4; ++i) {
      const int idd = i * 256 + t;
      const int r = idd >> 3, cch = (idd & 7) << 3;
      __builtin_amdgcn_global_load_lds(
          (const __attribute__((address_space(1))) unsigned*)(Ab + (size_t)(c0 + r) * Q_ + kOff + cch),
          (__attribute__((address_space(3))) unsigned*)(As + idd * 8), 16, 0, 0);
    }
#pragma unroll
    for (int i = 0; i < 4; ++i) {
      const int idd = i * 256 + t;
      const int r = idd >> 3, cch = (idd & 7) << 3;
      __builtin_amdgcn_global_load_lds(
          (const __attribute__((address_space(1))) unsigned*)(Bb + (size_t)(h0 + r) * Q_ + kOff + cch),
          (__attribute__((address_space(3))) unsigned*)(Bs + idd * 8), 16, 0, 0);
    }
    asm volatile("s_waitcnt vmcnt(0)" ::: "memory");
    __syncthreads();  // staged tiles visible to all waves

#pragma unroll
    for (int ks = 0; ks < 2; ++ks) {
      const int ko = ks * 32 + fk;
      bf16x8 af[4], bfr[4];
#pragma unroll
      for (int m = 0; m < 4; ++m)
        af[m] = *reinterpret_cast<const bf16x8*>(&As[(wm + m * 16 + fr) * BK + ko]);
#pragma unroll
      for (int n = 0; n < 4; ++n)
        bfr[n] = *reinterpret_cast<const bf16x8*>(&Bs[(wn + n * 16 + fr) * BK + ko]);
#pragma unroll
      for (int m = 0; m < 4; ++m)
#pragma unroll
        for (int n = 0; n < 4; ++n)
          acc[m][n] = __builtin_amdgcn_mfma_f32_16x16x32_bf16(af[m], bfr[n], acc[m][n], 0, 0, 0);
    }
  }

  // Epilogue: C/D layout col = lane&15, row = (lane>>4)*4 + j  (m89-verified)
  float* ob = out + (size_t)b * C_ * H_;
  const int orow = c0 + wm + ((lane >> 4) << 2);
  const int ocol = h0 + wn + fr;
#pragma unroll
  for (int m = 0; m < 4; ++m)
#pragma unroll
    for (int n = 0; n < 4; ++n) {
#pragma unroll
      for (int j = 0; j < 4; ++j)
        ob[(size_t)(orow + m * 16 + j) * H_ + (ocol + n * 16)] = acc[m][n][j];
    }
}

// ---------------------------------------------------------------------------
extern "C" void kernel_launch(void* const* d_in, const int* in_sizes, int n_in,
                              void* d_out, int out_size, void* d_ws, size_t ws_size,
                              hipStream_t stream) {
  const float* sim  = (const float*)d_in[0];   // [B, C, Q] f32
  const float* qenc = (const float*)d_in[1];   // [B, Q, H] f32
  float* out = (float*)d_out;                  // [B, C, H] f32

  // workspace: attn bf16 (64 MB) then transposed qenc bf16 (32 MB)
  ushort_t* attn = (ushort_t*)d_ws;
  ushort_t* qt   = (ushort_t*)((char*)d_ws + (size_t)B_ * C_ * Q_ * sizeof(ushort_t));

  softmax_bf16<<<(B_ * C_) / 4, 256, 0, stream>>>(sim, attn);
  qenc_convert<<<dim3(H_ / 64, Q_ / 64, B_), 256, 0, stream>>>(qenc, qt);
  gemm_bt<<<4096, 256, 0, stream>>>(attn, qt, out);
}

// Round 6
// 518.176 us; speedup vs baseline: 1.3880x; 1.0005x over previous
//
#include <hip/hip_runtime.h>
#include <hip/hip_bf16.h>

typedef unsigned short ushort_t;
typedef __bf16 bf16x8 __attribute__((ext_vector_type(8)));
typedef float f32x4 __attribute__((ext_vector_type(4)));

#define B_  32
#define C_  2048
#define Q_  512
#define H_  1024

// float -> bf16 round-to-nearest-even
__device__ __forceinline__ unsigned short f2bf(float f) {
  unsigned u = __float_as_uint(f);
  u += 0x7FFFu + ((u >> 16) & 1u);
  return (unsigned short)(u >> 16);
}

// ---------------------------------------------------------------------------
// K1: per-row softmax over Q=512, emit bf16.
// One wave per (b,c) row. Lane holds elements [4L..4L+3] and [256+4L..+3]
// (fully-coalesced float4 loads; reductions are order-agnostic; stores keep
// each element at its correct q position).
// ---------------------------------------------------------------------------
__global__ __launch_bounds__(256) void softmax_bf16(const float* __restrict__ sim,
                                                    ushort_t* __restrict__ attn) {
  const int row  = (blockIdx.x << 2) | (threadIdx.x >> 6);
  const int lane = threadIdx.x & 63;
  const float4* rp = reinterpret_cast<const float4*>(sim + (size_t)row * Q_);
  float4 v0 = rp[lane];        // q = 4*lane + j
  float4 v1 = rp[64 + lane];   // q = 256 + 4*lane + j
  float x[8] = {v0.x, v0.y, v0.z, v0.w, v1.x, v1.y, v1.z, v1.w};

  float mx = x[0];
#pragma unroll
  for (int j = 1; j < 8; ++j) mx = fmaxf(mx, x[j]);
#pragma unroll
  for (int s = 32; s > 0; s >>= 1) mx = fmaxf(mx, __shfl_xor(mx, s, 64));

  float e[8], sum = 0.f;
#pragma unroll
  for (int j = 0; j < 8; ++j) { e[j] = __expf(x[j] - mx); sum += e[j]; }
#pragma unroll
  for (int s = 32; s > 0; s >>= 1) sum += __shfl_xor(sum, s, 64);
  const float inv = 1.0f / sum;

  union { ushort_t s[4]; uint2 v; } a, b;
#pragma unroll
  for (int j = 0; j < 4; ++j) {
    a.s[j] = f2bf(e[j] * inv);
    b.s[j] = f2bf(e[4 + j] * inv);
  }
  ushort_t* orow = attn + (size_t)row * Q_;
  *reinterpret_cast<uint2*>(orow + lane * 4)       = a.v;
  *reinterpret_cast<uint2*>(orow + 256 + lane * 4) = b.v;
}

// ---------------------------------------------------------------------------
// K1b: transpose-convert qencode [B][Q][H] f32 -> qt [B][H][512] bf16,
// qt[b][h][q] = bf16(qenc[b][q][h]). 64x64 LDS tile transpose per block.
// Load phase vectorized: float4/lane (G13), 16 lanes cover one 64-float row.
// ---------------------------------------------------------------------------
__global__ __launch_bounds__(256) void qenc_convert(const float* __restrict__ qe,
                                                    ushort_t* __restrict__ qt) {
  __shared__ float tile[64][65];
  const int b  = blockIdx.z;
  const int q0 = blockIdx.y << 6;
  const int h0 = blockIdx.x << 6;

  const float* src = qe + ((size_t)b * Q_ + q0) * H_ + h0;
#pragma unroll
  for (int i = 0; i < 4; ++i) {
    const int idx = i * 256 + threadIdx.x;
    const int r  = idx >> 4;          // q row within tile (0..63)
    const int c4 = (idx & 15) << 2;   // h col within tile (0,4,..,60)
    const float4 v = *reinterpret_cast<const float4*>(src + (size_t)r * H_ + c4);
    tile[r][c4 + 0] = v.x;
    tile[r][c4 + 1] = v.y;
    tile[r][c4 + 2] = v.z;
    tile[r][c4 + 3] = v.w;
  }
  __syncthreads();

  const int hh = threadIdx.x >> 2;         // 0..63  (output row within h-tile)
  const int qs = (threadIdx.x & 3) << 4;   // 0,16,32,48 (q start within tile)
  ushort_t* dst = qt + ((size_t)b * H_ + h0 + hh) * Q_ + q0 + qs;

  union { ushort_t s[8]; uint4 v; } ha, hb;
#pragma unroll
  for (int j = 0; j < 8; ++j) {
    ha.s[j] = f2bf(tile[qs + j][hh]);
    hb.s[j] = f2bf(tile[qs + 8 + j][hh]);
  }
  *reinterpret_cast<uint4*>(dst)     = ha.v;
  *reinterpret_cast<uint4*>(dst + 8) = hb.v;
}

// ---------------------------------------------------------------------------
// K2: per-batch GEMM  out[c][h] = sum_q attn[c][q] * qt[h][q],  K = 512.
// 128x128 tile, BK=64, 4 waves (2x2 of 64x64), mfma_f32_16x16x32_bf16.
// T1 XCD swizzle: 4096 blocks, each XCD gets 512 contiguous tiles
// (= 4 whole batches; per-batch operands 3 MB < 4 MB L2).
// UNCHANGED from round 5 (A/B control for the K1/K1b fix).
// ---------------------------------------------------------------------------
__global__ __launch_bounds__(256) void gemm_bt(const ushort_t* __restrict__ A,
                                               const ushort_t* __restrict__ Bt,
                                               float* __restrict__ out) {
  constexpr int BK = 64;
  __shared__ ushort_t As[128 * BK];
  __shared__ ushort_t Bs[128 * BK];

  // XCD-aware swizzle (nwg = 4096, nwg % 8 == 0 -> simple bijective form)
  const int id = blockIdx.x;
  const int sw = (id & 7) * 512 + (id >> 3);
  const int b   = sw >> 7;          // batch
  const int rem = sw & 127;         // 16 c-tiles x 8 h-tiles
  const int c0 = (rem >> 3) << 7;
  const int h0 = (rem & 7) << 7;

  const int t    = threadIdx.x;
  const int lane = t & 63;
  const int w    = t >> 6;
  const int wm = (w >> 1) << 6;  // wave row offset: 0 / 64
  const int wn = (w & 1) << 6;   // wave col offset: 0 / 64

  const ushort_t* Ab = A  + (size_t)b * C_ * Q_;
  const ushort_t* Bb = Bt + (size_t)b * H_ * Q_;

  f32x4 acc[4][4];
#pragma unroll
  for (int m = 0; m < 4; ++m)
#pragma unroll
    for (int n = 0; n < 4; ++n) acc[m][n] = (f32x4){0.f, 0.f, 0.f, 0.f};

  const int fr = lane & 15;        // fragment row (A) / col (B)
  const int fk = (lane >> 4) * 8;  // fragment k-offset

  for (int kt = 0; kt < 8; ++kt) {     // K = 512, BK = 64
    const int kOff = kt * BK;

    __syncthreads();  // all waves done reading previous LDS tiles
#pragma unroll
    for (int i = 0; i < 4; ++i) {
      const int idd = i * 256 + t;
      const int r = idd >> 3, cch = (idd & 7) << 3;
      __builtin_amdgcn_global_load_lds(
          (const __attribute__((address_space(1))) unsigned*)(Ab + (size_t)(c0 + r) * Q_ + kOff + cch),
          (__attribute__((address_space(3))) unsigned*)(As + idd * 8), 16, 0, 0);
    }
#pragma unroll
    for (int i = 0; i < 4; ++i) {
      const int idd = i * 256 + t;
      const int r = idd >> 3, cch = (idd & 7) << 3;
      __builtin_amdgcn_global_load_lds(
          (const __attribute__((address_space(1))) unsigned*)(Bb + (size_t)(h0 + r) * Q_ + kOff + cch),
          (__attribute__((address_space(3))) unsigned*)(Bs + idd * 8), 16, 0, 0);
    }
    asm volatile("s_waitcnt vmcnt(0)" ::: "memory");
    __syncthreads();  // staged tiles visible to all waves

#pragma unroll
    for (int ks = 0; ks < 2; ++ks) {
      const int ko = ks * 32 + fk;
      bf16x8 af[4], bfr[4];
#pragma unroll
      for (int m = 0; m < 4; ++m)
        af[m] = *reinterpret_cast<const bf16x8*>(&As[(wm + m * 16 + fr) * BK + ko]);
#pragma unroll
      for (int n = 0; n < 4; ++n)
        bfr[n] = *reinterpret_cast<const bf16x8*>(&Bs[(wn + n * 16 + fr) * BK + ko]);
#pragma unroll
      for (int m = 0; m < 4; ++m)
#pragma unroll
        for (int n = 0; n < 4; ++n)
          acc[m][n] = __builtin_amdgcn_mfma_f32_16x16x32_bf16(af[m], bfr[n], acc[m][n], 0, 0, 0);
    }
  }

  // Epilogue: C/D layout col = lane&15, row = (lane>>4)*4 + j  (m89-verified)
  float* ob = out + (size_t)b * C_ * H_;
  const int orow = c0 + wm + ((lane >> 4) << 2);
  const int ocol = h0 + wn + fr;
#pragma unroll
  for (int m = 0; m < 4; ++m)
#pragma unroll
    for (int n = 0; n < 4; ++n) {
#pragma unroll
      for (int j = 0; j < 4; ++j)
        ob[(size_t)(orow + m * 16 + j) * H_ + (ocol + n * 16)] = acc[m][n][j];
    }
}

// ---------------------------------------------------------------------------
extern "C" void kernel_launch(void* const* d_in, const int* in_sizes, int n_in,
                              void* d_out, int out_size, void* d_ws, size_t ws_size,
                              hipStream_t stream) {
  const float* sim  = (const float*)d_in[0];   // [B, C, Q] f32
  const float* qenc = (const float*)d_in[1];   // [B, Q, H] f32
  float* out = (float*)d_out;                  // [B, C, H] f32

  // workspace: attn bf16 (64 MB) then transposed qenc bf16 (32 MB)
  ushort_t* attn = (ushort_t*)d_ws;
  ushort_t* qt   = (ushort_t*)((char*)d_ws + (size_t)B_ * C_ * Q_ * sizeof(ushort_t));

  softmax_bf16<<<(B_ * C_) / 4, 256, 0, stream>>>(sim, attn);
  qenc_convert<<<dim3(H_ / 64, Q_ / 64, B_), 256, 0, stream>>>(qenc, qt);
  gemm_bt<<<4096, 256, 0, stream>>>(attn, qt, out);
}

// Round 8
// 491.794 us; speedup vs baseline: 1.4625x; 1.0536x over previous
//
#include <hip/hip_runtime.h>
#include <hip/hip_bf16.h>

typedef unsigned short ushort_t;
typedef __bf16 bf16x8 __attribute__((ext_vector_type(8)));
typedef float f32x4 __attribute__((ext_vector_type(4)));

#define B_  32
#define C_  2048
#define Q_  512
#define H_  1024

// float -> bf16 round-to-nearest-even
__device__ __forceinline__ unsigned short f2bf(float f) {
  unsigned u = __float_as_uint(f);
  u += 0x7FFFu + ((u >> 16) & 1u);
  return (unsigned short)(u >> 16);
}

// ---------------------------------------------------------------------------
// K1: per-row softmax over Q=512, emit bf16. One wave per (b,c) row.
// ---------------------------------------------------------------------------
__global__ __launch_bounds__(256) void softmax_bf16(const float* __restrict__ sim,
                                                    ushort_t* __restrict__ attn) {
  const int row  = (blockIdx.x << 2) | (threadIdx.x >> 6);
  const int lane = threadIdx.x & 63;
  const float4* rp = reinterpret_cast<const float4*>(sim + (size_t)row * Q_);
  float4 v0 = rp[lane];        // q = 4*lane + j
  float4 v1 = rp[64 + lane];   // q = 256 + 4*lane + j
  float x[8] = {v0.x, v0.y, v0.z, v0.w, v1.x, v1.y, v1.z, v1.w};

  float mx = x[0];
#pragma unroll
  for (int j = 1; j < 8; ++j) mx = fmaxf(mx, x[j]);
#pragma unroll
  for (int s = 32; s > 0; s >>= 1) mx = fmaxf(mx, __shfl_xor(mx, s, 64));

  float e[8], sum = 0.f;
#pragma unroll
  for (int j = 0; j < 8; ++j) { e[j] = __expf(x[j] - mx); sum += e[j]; }
#pragma unroll
  for (int s = 32; s > 0; s >>= 1) sum += __shfl_xor(sum, s, 64);
  const float inv = 1.0f / sum;

  union { ushort_t s[4]; uint2 v; } a, b;
#pragma unroll
  for (int j = 0; j < 4; ++j) {
    a.s[j] = f2bf(e[j] * inv);
    b.s[j] = f2bf(e[4 + j] * inv);
  }
  ushort_t* orow = attn + (size_t)row * Q_;
  *reinterpret_cast<uint2*>(orow + lane * 4)       = a.v;
  *reinterpret_cast<uint2*>(orow + 256 + lane * 4) = b.v;
}

// ---------------------------------------------------------------------------
// K1b: transpose-convert qencode [B][Q][H] f32 -> qt [B][H][512] bf16.
// 64x64 LDS tile transpose per block, float4 loads.
// ---------------------------------------------------------------------------
__global__ __launch_bounds__(256) void qenc_convert(const float* __restrict__ qe,
                                                    ushort_t* __restrict__ qt) {
  __shared__ float tile[64][65];
  const int b  = blockIdx.z;
  const int q0 = blockIdx.y << 6;
  const int h0 = blockIdx.x << 6;

  const float* src = qe + ((size_t)b * Q_ + q0) * H_ + h0;
#pragma unroll
  for (int i = 0; i < 4; ++i) {
    const int idx = i * 256 + threadIdx.x;
    const int r  = idx >> 4;          // q row within tile (0..63)
    const int c4 = (idx & 15) << 2;   // h col within tile
    const float4 v = *reinterpret_cast<const float4*>(src + (size_t)r * H_ + c4);
    tile[r][c4 + 0] = v.x;
    tile[r][c4 + 1] = v.y;
    tile[r][c4 + 2] = v.z;
    tile[r][c4 + 3] = v.w;
  }
  __syncthreads();

  const int hh = threadIdx.x >> 2;         // output row within h-tile
  const int qs = (threadIdx.x & 3) << 4;   // q start within tile
  ushort_t* dst = qt + ((size_t)b * H_ + h0 + hh) * Q_ + q0 + qs;

  union { ushort_t s[8]; uint4 v; } ha, hb;
#pragma unroll
  for (int j = 0; j < 8; ++j) {
    ha.s[j] = f2bf(tile[qs + j][hh]);
    hb.s[j] = f2bf(tile[qs + 8 + j][hh]);
  }
  *reinterpret_cast<uint4*>(dst)     = ha.v;
  *reinterpret_cast<uint4*>(dst + 8) = hb.v;
}

// ---------------------------------------------------------------------------
// K2: per-batch GEMM  out[c][h] = sum_q attn[c][q] * qt[h][q],  K = 512.
// 256x256 tile, BK=64, 512 threads = 8 waves (2x4), per-wave 128x64 output.
// Double-buffered LDS (128 KB), ONE barrier + vmcnt(0) per K-tile:
//   stage(next tile -> buf^1); ds_read+MFMA(buf); vmcnt(0); barrier; flip.
// (T3-minimum 2-phase recipe; m230-V0-class ~680 TF structure.)
// XCD swizzle: 1024 blocks, 128/XCD = 4 contiguous batches per XCD.
// ---------------------------------------------------------------------------
__global__ __launch_bounds__(512) void gemm_bt(const ushort_t* __restrict__ A,
                                               const ushort_t* __restrict__ Bt,
                                               float* __restrict__ out) {
  constexpr int BK = 64;
  __shared__ ushort_t As[2][256 * BK];   // 2 x 32 KB
  __shared__ ushort_t Bs[2][256 * BK];   // 2 x 32 KB

  // XCD-aware swizzle (nwg = 1024, % 8 == 0 -> simple bijective form)
  const int id = blockIdx.x;
  const int sw = (id & 7) * 128 + (id >> 3);
  const int b   = sw >> 5;          // batch (32 tiles per batch)
  const int rem = sw & 31;          // 8 c-tiles x 4 h-tiles
  const int c0 = (rem >> 2) << 8;
  const int h0 = (rem & 3) << 8;

  const int t    = threadIdx.x;
  const int lane = t & 63;
  const int w    = t >> 6;          // 0..7
  const int wm = (w >> 2) << 7;     // wave row offset: 0 / 128
  const int wn = (w & 3) << 6;      // wave col offset: 0/64/128/192

  const ushort_t* Ab = A  + (size_t)b * C_ * Q_;
  const ushort_t* Bb = Bt + (size_t)b * H_ * Q_;

  f32x4 acc[8][4];
#pragma unroll
  for (int m = 0; m < 8; ++m)
#pragma unroll
    for (int n = 0; n < 4; ++n) acc[m][n] = (f32x4){0.f, 0.f, 0.f, 0.f};

  const int fr = lane & 15;        // fragment row (A) / col (B)
  const int fk = (lane >> 4) * 8;  // fragment k-offset

  // stage one K-tile (A 256x64 + B 256x64) into buffer `buf`
  auto stage = [&](int buf, int kOff) {
#pragma unroll
    for (int i = 0; i < 4; ++i) {
      const int idd = i * 512 + t;
      const int r = idd >> 3, cc = (idd & 7) << 3;
      __builtin_amdgcn_global_load_lds(
          (const __attribute__((address_space(1))) unsigned*)(Ab + (size_t)(c0 + r) * Q_ + kOff + cc),
          (__attribute__((address_space(3))) unsigned*)(&As[buf][idd * 8]), 16, 0, 0);
      __builtin_amdgcn_global_load_lds(
          (const __attribute__((address_space(1))) unsigned*)(Bb + (size_t)(h0 + r) * Q_ + kOff + cc),
          (__attribute__((address_space(3))) unsigned*)(&Bs[buf][idd * 8]), 16, 0, 0);
    }
  };

  // prologue: stage K-tile 0
  stage(0, 0);
  asm volatile("s_waitcnt vmcnt(0)" ::: "memory");
  __syncthreads();

  int cur = 0;
  for (int kt = 0; kt < 8; ++kt) {     // K = 512, BK = 64
    if (kt < 7) stage(cur ^ 1, (kt + 1) * BK);   // prefetch next tile

#pragma unroll
    for (int ks = 0; ks < 2; ++ks) {
      const int ko = ks * 32 + fk;
      bf16x8 af[8], bfr[4];
#pragma unroll
      for (int m = 0; m < 8; ++m)
        af[m] = *reinterpret_cast<const bf16x8*>(&As[cur][(wm + m * 16 + fr) * BK + ko]);
#pragma unroll
      for (int n = 0; n < 4; ++n)
        bfr[n] = *reinterpret_cast<const bf16x8*>(&Bs[cur][(wn + n * 16 + fr) * BK + ko]);
#pragma unroll
      for (int m = 0; m < 8; ++m)
#pragma unroll
        for (int n = 0; n < 4; ++n)
          acc[m][n] = __builtin_amdgcn_mfma_f32_16x16x32_bf16(af[m], bfr[n], acc[m][n], 0, 0, 0);
    }

    asm volatile("s_waitcnt vmcnt(0)" ::: "memory");  // next tile fully landed
    __syncthreads();                                  // + all waves done reading cur
    cur ^= 1;
  }

  // Epilogue: C/D layout col = lane&15, row = (lane>>4)*4 + j
  float* ob = out + (size_t)b * C_ * H_;
  const int orow = c0 + wm + ((lane >> 4) << 2);
  const int ocol = h0 + wn + fr;
#pragma unroll
  for (int m = 0; m < 8; ++m)
#pragma unroll
    for (int n = 0; n < 4; ++n) {
#pragma unroll
      for (int j = 0; j < 4; ++j)
        ob[(size_t)(orow + m * 16 + j) * H_ + (ocol + n * 16)] = acc[m][n][j];
    }
}

// ---------------------------------------------------------------------------
extern "C" void kernel_launch(void* const* d_in, const int* in_sizes, int n_in,
                              void* d_out, int out_size, void* d_ws, size_t ws_size,
                              hipStream_t stream) {
  const float* sim  = (const float*)d_in[0];   // [B, C, Q] f32
  const float* qenc = (const float*)d_in[1];   // [B, Q, H] f32
  float* out = (float*)d_out;                  // [B, C, H] f32

  // workspace: attn bf16 (64 MB) then transposed qenc bf16 (32 MB)
  ushort_t* attn = (ushort_t*)d_ws;
  ushort_t* qt   = (ushort_t*)((char*)d_ws + (size_t)B_ * C_ * Q_ * sizeof(ushort_t));

  softmax_bf16<<<(B_ * C_) / 4, 256, 0, stream>>>(sim, attn);
  qenc_convert<<<dim3(H_ / 64, Q_ / 64, B_), 256, 0, stream>>>(qenc, qt);
  gemm_bt<<<1024, 512, 0, stream>>>(attn, qt, out);
}